// Round 8
// baseline (133.760 us; speedup 1.0000x reference)
//
#include <hip/hip_runtime.h>

// Problem constants (fixed by the reference).
#define B_    8
#define N_    6000
#define C_    21
#define MAXT  200
#define NEGV  -1000000000.0f
#define UCAP  4096      // LDS capacity for unordered candidate keys (M ~2880)
#define CCAP  1024      // chunk capacity (hard); pick targets ~512
#define CTGT  512       // chunk pick target (walk consumes ~235 elements)
#define NBUCK 64        // score buckets = mantissa bits 22..17
#define NTH   1024
#define NENT  (C_ * MAXT)   // 4200 entries per batch

__device__ __forceinline__ unsigned ford(float f) {
  unsigned u = __float_as_uint(f);
  return (u & 0x80000000u) ? ~u : (u | 0x80000000u);  // order-preserving bits
}
__device__ __forceinline__ float funord(unsigned o) {
  unsigned u = (o & 0x80000000u) ? (o ^ 0x80000000u) : ~o;
  return __uint_as_float(u);
}

// Box decode — expression order matches the numpy reference exactly (absmax 0.0
// verified rounds 1-7); keep fp contract off.
__device__ __forceinline__ float4 decode_box(const float* __restrict__ roi,
                                             const float* __restrict__ deltas,
                                             int b, int n, int c)
{
#pragma clang fp contract(off)
  float4 r = *(const float4*)(roi + ((size_t)b * N_ + n) * 4);
  float4 d = *(const float4*)(deltas + ((size_t)b * N_ + n) * (C_ * 4) + c * 4);
  float d0 = d.x * 0.1f, d1 = d.y * 0.1f, d2 = d.z * 0.2f, d3 = d.w * 0.2f;
  float ah = r.z - r.x, aw = r.w - r.y;
  float acy = r.x + 0.5f * ah, acx = r.y + 0.5f * aw;
  float bh = expf(d2) * ah, bw = expf(d3) * aw;
  float bcy = d0 * ah + acy, bcx = d1 * aw + acx;
  float y1 = bcy - 0.5f * bh, x1 = bcx - 0.5f * bw;
  float y2 = y1 + bh, x2 = x1 + bw;
  y1 = fminf(fmaxf(y1, 0.f), 1.f); x1 = fminf(fmaxf(x1, 0.f), 1.f);
  y2 = fminf(fmaxf(y2, 0.f), 1.f); x2 = fminf(fmaxf(x2, 0.f), 1.f);
  return make_float4(y1, x1, y2, x2);
}

// IoU with the reference's exact association: ((sel_a + area) - inter) + 1e-8.
__device__ __forceinline__ float iou_ref(float4 s, float4 o) {
#pragma clang fp contract(off)
  float iy1 = fmaxf(s.x, o.x), ix1 = fmaxf(s.y, o.y);
  float iy2 = fminf(s.z, o.z), ix2 = fminf(s.w, o.w);
  float inter = fmaxf(iy2 - iy1, 0.f) * fmaxf(ix2 - ix1, 0.f);
  float sa = fmaxf(s.z - s.x, 0.f) * fmaxf(s.w - s.y, 0.f);
  float oa = fmaxf(o.z - o.x, 0.f) * fmaxf(o.w - o.y, 0.f);
  return inter / (sa + oa - inter + 1e-08f);
}

// One block per (b,c). Phase 1 now fuses the per-anchor argmax (formerly
// label_kernel): identical argmax expression (strict >, first max wins), so
// cand/sc are bit-identical to the rounds-4..7 pipeline. Phase 2: histogram-
// chunked bitonic sort + batched walk (round-5/7 logic) with three audited
// deltas: chunk target 512 + dynamic sort width; whole-chunk upfront decode;
// per-wave s_dead[] slots instead of atomicOr'd s_supmask (no reset hazard).
__global__ __launch_bounds__(NTH) void nms_kernel(
    const float* __restrict__ roi, const float* __restrict__ deltas,
    const float* __restrict__ probs,
    float* __restrict__ sel_val, float* __restrict__ sel_box)
{
#pragma clang fp contract(off)
  const int bc = blockIdx.x, b = bc / C_, c = bc % C_;
  const int tid = threadIdx.x, lane = tid & 63, wv = tid >> 6;

  __shared__ unsigned long long ukeys[UCAP];     // unordered candidate keys
  __shared__ unsigned long long cbuf[CCAP];      // current chunk (sorted)
  __shared__ float4 cboxAll[CCAP];               // decoded chunk boxes
  __shared__ float4 comm[MAXT];                  // committed (selected) boxes
  __shared__ unsigned long long kill[64];        // intra-batch kill rows
  __shared__ unsigned long long s_dead[16];      // per-wave vs-committed masks
  __shared__ int hist[NBUCK];
  __shared__ int s_cnt, s_clen, s_ncomm, s_blo, s_len;

  if (tid < NBUCK) hist[tid] = 0;
  if (tid == 0) { s_cnt = 0; s_ncomm = 0; }
  __syncthreads();

  // ---- Phase 1: inline argmax + threshold + collect keys + histogram ----
  // (scores in (0.5,1) => exponent fixed at 126 => mantissa bits are a
  //  monotone prefix of ford(score); bucket = mantissa bits 22..17)
  for (int base0 = 0; base0 < N_; base0 += NTH) {
    int n = base0 + tid;
    bool cand = false;
    float sc = 0.f;
    if (n < N_) {
      const float* pr = probs + ((size_t)b * N_ + n) * C_;
      float mx = pr[0]; int am = 0;
      #pragma unroll
      for (int k = 1; k < C_; ++k) { float v = pr[k]; if (v > mx) { mx = v; am = k; } }
      if (am != 0) sc = pr[c];
      cand = (sc > 0.5f);
    }
    unsigned long long m = __ballot(cand);
    int wcnt = __popcll(m);
    int bslot = 0;
    if (lane == 0 && wcnt) bslot = atomicAdd(&s_cnt, wcnt);
    bslot = __shfl(bslot, 0);
    if (cand) {
      int pos = bslot + __popcll(m & ((1ULL << lane) - 1ULL));
      if (pos < UCAP) {
        unsigned hi = ford(sc);
        ukeys[pos] = ((unsigned long long)hi << 32) |
                     (unsigned)(0xFFFFFFFFu - (unsigned)n);
        atomicAdd(&hist[(hi >> 17) & (NBUCK - 1)], 1);
      }
    }
  }
  __syncthreads();
  int M = s_cnt < UCAP ? s_cnt : UCAP;

  float* sv = sel_val + (size_t)bc * MAXT;
  float* sb = sel_box + (size_t)bc * MAXT * 4;

  // ---- Phase 2: chunked sort + walk ----
  int bhi = NBUCK - 1;
  while (true) {
    if (s_ncomm >= MAXT || bhi < 0) break;

    // pick bucket range [blo, bhi]: accumulate toward CTGT; always take >=1
    // bucket (oversized singleton allowed up to CCAP). Bucket boundaries
    // preserve global descending key order across chunks.
    if (tid == 0) {
      int tot = 0, lo = bhi;
      while (lo >= 0) {
        int t2 = tot + hist[lo];
        if (t2 > CTGT && tot > 0) break;
        tot = t2; --lo;
        if (tot > CTGT) break;
      }
      s_blo = lo + 1; s_len = tot; s_clen = 0;
    }
    __syncthreads();
    int blo = s_blo;
    if (s_len == 0) break;            // all remaining buckets empty

    // gather chunk members from unordered keys (order random; sort fixes it)
    for (int i = tid; i < M; i += NTH) {
      unsigned long long kk = ukeys[i];
      int bk = (int)((kk >> 49) & (NBUCK - 1));
      bool in = (bk >= blo && bk <= bhi);
      unsigned long long mm = __ballot(in);
      int wc = __popcll(mm);
      int bs0 = 0;
      if (lane == 0 && wc) bs0 = atomicAdd(&s_clen, wc);
      bs0 = __shfl(bs0, 0);
      if (in) {
        int p = bs0 + __popcll(mm & ((1ULL << lane) - 1ULL));
        if (p < CCAP) cbuf[p] = kk;
      }
    }
    __syncthreads();
    int alen = s_clen < CCAP ? s_clen : CCAP;

    if (alen > 0) {
      // dynamic sort width: smallest pow2 >= alen (uniform value)
      int SORTP = 64;
      while (SORTP < alen) SORTP <<= 1;

      // bitonic sort desc, 1 elem/lane: j<64 via shfl_xor, j>=64 via LDS.
      // Lanes >= SORTP carry 0 and only ever exchange with lanes >= SORTP
      // (tid^j >= SORTP for tid >= SORTP, j < SORTP), so the sorted region
      // is unaffected. Pads (0) sink below all real keys (top bit set).
      {
        unsigned long long v = (tid < alen) ? cbuf[tid] : 0ULL;
        for (int k = 2; k <= SORTP; k <<= 1) {
          for (int j = k >> 1; j > 0; j >>= 1) {
            bool takeMax = ((tid & j) == 0) == ((tid & k) == 0);
            unsigned long long w;
            if (j >= 64) {
              __syncthreads(); cbuf[tid] = v; __syncthreads();
              w = cbuf[tid ^ j];
            } else {
              w = __shfl_xor(v, j);
            }
            if ((w > v) == takeMax) v = w;
          }
        }
        __syncthreads(); cbuf[tid] = v; __syncthreads();
      }

      // upfront decode of the whole sorted chunk (one barrier, full width)
      if (tid < alen) {
        int n = (int)(0xFFFFFFFFu - (unsigned)(cbuf[tid] & 0xFFFFFFFFull));
        cboxAll[tid] = decode_box(roi, deltas, b, n, c);
      }
      __syncthreads();

      // walk the sorted chunk in batches of 64 (2 barriers per batch)
      int start = 0;
      while (true) {
        int nc = s_ncomm;
        if (nc >= MAXT || start >= alen) break;
        int bs = min(64, alen - start);

        float4 ib = cboxAll[start + lane];   // lane >= bs -> garbage, masked below
        // intra-batch kill rows: wave wv owns rows j = 4*wv + r (ballots)
        #pragma unroll
        for (int r = 0; r < 4; ++r) {
          int j = (wv << 2) | r;
          float4 jb4 = cboxAll[start + j];   // wave-uniform -> LDS broadcast
          bool kf = (j < bs) && (lane < bs) && (lane > j) &&
                    (iou_ref(jb4, ib) > 0.5f);
          unsigned long long rowm = __ballot(kf);
          if (lane == 0) kill[j] = rowm;
        }
        // vs-committed test: wave wv covers comm[wv::16]; each wave writes
        // its own s_dead slot unconditionally (no reset, no atomics)
        {
          bool dead = false;
          if (lane < bs) {
            for (int jc = wv; jc < nc; jc += 16) {
              if (iou_ref(comm[jc], ib) > 0.5f) { dead = true; break; }
            }
          }
          unsigned long long dm = __ballot(dead);
          if (lane == 0) s_dead[wv] = dm;
        }
        __syncthreads();

        // serial resolve in wave 0: bit-ops + shfl row broadcast (round-5/7
        // logic, verified deterministic under graph replay)
        if (wv == 0) {
          unsigned long long sup = s_dead[0];
          for (int w2 = 1; w2 < 16; ++w2) sup |= s_dead[w2];
          unsigned long long myrow = kill[lane];
          unsigned long long alive = ~sup;
          if (bs < 64) alive &= ((1ULL << bs) - 1ULL);
          unsigned long long chosen = 0ULL;
          int cnt = nc;
          for (int j = 0; j < bs && cnt < MAXT; ++j) {
            if (!((alive >> j) & 1ULL)) continue;
            chosen |= (1ULL << j);
            ++cnt;
            alive &= ~__shfl(myrow, j);
          }
          if ((chosen >> lane) & 1ULL) {
            int rnk = nc + __popcll(chosen & ((1ULL << lane) - 1ULL));
            float4 bb2 = cboxAll[start + lane];
            comm[rnk] = bb2;
            sv[rnk] = funord((unsigned)(cbuf[start + lane] >> 32));
            sb[(size_t)rnk * 4 + 0] = bb2.x; sb[(size_t)rnk * 4 + 1] = bb2.y;
            sb[(size_t)rnk * 4 + 2] = bb2.z; sb[(size_t)rnk * 4 + 3] = bb2.w;
          }
          if (lane == 0) s_ncomm = cnt;
        }
        __syncthreads();
        start += bs;
      }
    }
    bhi = blo - 1;
  }

  // remaining steps invalid -> sel_val = NEG (boxes never read for these)
  int T = s_ncomm;
  for (int j2 = T + tid; j2 < MAXT; j2 += NTH) sv[j2] = NEGV;
}

// ---- Merge, stage 1: per-(b, searched-class) partial ranks (round-7
// verbatim). Scalar lo/hi in registers; entry-major partial layout.
__global__ __launch_bounds__(NTH) void rank_kernel(
    const float* __restrict__ sel_val, int* __restrict__ partial)
{
  const int blk = blockIdx.x;          // b * C_ + sc
  const int b = blk / C_, sc = blk % C_;
  const int tid = threadIdx.x;
  __shared__ unsigned long long lkeys[MAXT];

  if (tid < MAXT) {
    float v = sel_val[(size_t)b * NENT + sc * MAXT + tid];
    lkeys[tid] = ((unsigned long long)ford(v) << 32) |
                 (unsigned)(0xFFFFFFFFu - (unsigned)(sc * MAXT + tid));
  }
  __syncthreads();

  for (int e = tid; e < NENT; e += NTH) {
    float v = sel_val[(size_t)b * NENT + e];
    unsigned long long mykey = ((unsigned long long)ford(v) << 32) |
                               (unsigned)(0xFFFFFFFFu - (unsigned)e);
    int lo = 0, hi = MAXT;
    while (lo < hi) {
      int mid = (lo + hi) >> 1;
      if (lkeys[mid] > mykey) lo = mid + 1; else hi = mid;
    }
    partial[((size_t)b * NENT + e) * C_ + sc] = lo;
  }
}

// ---- Merge, stage 2: rank = sum of 21 contiguous partials -> scatter
// (round-7 verbatim). Ranks are a permutation of 0..NENT-1.
__global__ __launch_bounds__(256) void scatter_kernel(
    const float* __restrict__ sel_val, const float* __restrict__ sel_box,
    const int* __restrict__ partial, float* __restrict__ out)
{
  const int blk = blockIdx.x;          // b * C_ + sc
  const int b = blk / C_, sc = blk % C_;
  const int t = threadIdx.x;
  if (t >= MAXT) return;
  const int e = sc * MAXT + t;

  const int* pp = partial + ((size_t)b * NENT + e) * C_;
  int rank = 0;
  #pragma unroll
  for (int cc = 0; cc < C_; ++cc) rank += pp[cc];
  if (rank >= MAXT) return;

  float* obx = out + (size_t)b * MAXT * 4;                       // final_bboxes
  float* olb = out + (size_t)B_ * MAXT * 4 + (size_t)b * MAXT;   // final_labels
  float* osc = out + (size_t)B_ * MAXT * 5 + (size_t)b * MAXT;   // final_scores

  float v = sel_val[(size_t)b * NENT + e];
  if (v > NEGV * 0.5f) {
    osc[rank] = v;
    olb[rank] = (float)sc;
    const float* bp = sel_box + ((size_t)b * NENT + e) * 4;
    obx[rank * 4 + 0] = bp[0]; obx[rank * 4 + 1] = bp[1];
    obx[rank * 4 + 2] = bp[2]; obx[rank * 4 + 3] = bp[3];
  } else {
    osc[rank] = 0.f; olb[rank] = 0.f;
    obx[rank * 4 + 0] = 0.f; obx[rank * 4 + 1] = 0.f;
    obx[rank * 4 + 2] = 0.f; obx[rank * 4 + 3] = 0.f;
  }
}

// Fallback merge (round-7 verbatim; used only if ws can't hold partials).
__global__ __launch_bounds__(NTH) void merge_kernel(
    const float* __restrict__ sel_val, const float* __restrict__ sel_box,
    float* __restrict__ out)
{
  const int b = blockIdx.x;
  const int tid = threadIdx.x;
  __shared__ float svl[NENT];
  for (int i = tid; i < NENT; i += NTH)
    svl[i] = sel_val[(size_t)b * NENT + i];
  __syncthreads();

  float* obx = out + (size_t)b * MAXT * 4;
  float* olb = out + (size_t)B_ * MAXT * 4 + (size_t)b * MAXT;
  float* osc = out + (size_t)B_ * MAXT * 5 + (size_t)b * MAXT;

  for (int e = tid; e < NENT; e += NTH) {
    float v = svl[e];
    unsigned long long mykey = ((unsigned long long)ford(v) << 32) |
                               (unsigned)(0xFFFFFFFFu - (unsigned)e);
    int rank = 0;
    for (int cc = 0; cc < C_; ++cc) {
      int lo = 0, hi = MAXT;
      while (lo < hi) {
        int mid = (lo + hi) >> 1;
        int ee = cc * MAXT + mid;
        unsigned long long k2 = ((unsigned long long)ford(svl[ee]) << 32) |
                                (unsigned)(0xFFFFFFFFu - (unsigned)ee);
        if (k2 > mykey) lo = mid + 1; else hi = mid;
      }
      rank += lo;
    }
    if (rank < MAXT) {
      if (v > NEGV * 0.5f) {
        osc[rank] = v;
        olb[rank] = (float)(e / MAXT);
        const float* bp = sel_box + ((size_t)b * NENT + e) * 4;
        obx[rank * 4 + 0] = bp[0]; obx[rank * 4 + 1] = bp[1];
        obx[rank * 4 + 2] = bp[2]; obx[rank * 4 + 3] = bp[3];
      } else {
        osc[rank] = 0.f; olb[rank] = 0.f;
        obx[rank * 4 + 0] = 0.f; obx[rank * 4 + 1] = 0.f;
        obx[rank * 4 + 2] = 0.f; obx[rank * 4 + 3] = 0.f;
      }
    }
  }
}

extern "C" void kernel_launch(void* const* d_in, const int* in_sizes, int n_in,
                              void* d_out, int out_size, void* d_ws, size_t ws_size,
                              hipStream_t stream)
{
  const float* roi    = (const float*)d_in[0];  // (8,6000,4)
  const float* deltas = (const float*)d_in[1];  // (8,6000,84)
  const float* probs  = (const float*)d_in[2];  // (8,6000,21)
  float* out = (float*)d_out;                   // 6400 + 1600 + 1600 floats
  float* ws  = (float*)d_ws;

  // ws layout (floats): sel_val[33600] | sel_box[134400] | partial[8*4200*21 ints]
  float* sel_val = ws;
  float* sel_box = ws + (size_t)B_ * NENT;
  int* partial = (int*)(ws + (size_t)B_ * NENT * 5);
  size_t need = ((size_t)B_ * NENT * 5 + (size_t)B_ * NENT * C_) * sizeof(float);

  nms_kernel<<<dim3(B_ * C_), dim3(NTH), 0, stream>>>(
      roi, deltas, probs, sel_val, sel_box);
  if (ws_size >= need) {
    rank_kernel<<<dim3(B_ * C_), dim3(NTH), 0, stream>>>(sel_val, partial);
    scatter_kernel<<<dim3(B_ * C_), dim3(256), 0, stream>>>(sel_val, sel_box, partial, out);
  } else {
    merge_kernel<<<dim3(B_), dim3(NTH), 0, stream>>>(sel_val, sel_box, out);
  }
}

// Round 9
// 123.246 us; speedup vs baseline: 1.0853x; 1.0853x over previous
//
#include <hip/hip_runtime.h>

// Problem constants (fixed by the reference).
#define B_    8
#define N_    6000
#define C_    21
#define MAXT  200
#define NEGV  -1000000000.0f
#define UCAP  4096      // LDS capacity for unordered candidate keys (M ~2880)
#define CCAP  1024      // chunk capacity (hard); pick targets ~512
#define CTGT  512       // chunk pick target (walk consumes ~235 elements)
#define NBUCK 64        // score buckets = mantissa bits 22..17
#define NTH   1024
#define NENT  (C_ * MAXT)   // 4200 entries per batch

__device__ __forceinline__ unsigned ford(float f) {
  unsigned u = __float_as_uint(f);
  return (u & 0x80000000u) ? ~u : (u | 0x80000000u);  // order-preserving bits
}
__device__ __forceinline__ float funord(unsigned o) {
  unsigned u = (o & 0x80000000u) ? (o ^ 0x80000000u) : ~o;
  return __uint_as_float(u);
}

// Box decode — expression order matches the numpy reference exactly (absmax 0.0
// verified rounds 1-8); keep fp contract off.
__device__ __forceinline__ float4 decode_box(const float* __restrict__ roi,
                                             const float* __restrict__ deltas,
                                             int b, int n, int c)
{
#pragma clang fp contract(off)
  float4 r = *(const float4*)(roi + ((size_t)b * N_ + n) * 4);
  float4 d = *(const float4*)(deltas + ((size_t)b * N_ + n) * (C_ * 4) + c * 4);
  float d0 = d.x * 0.1f, d1 = d.y * 0.1f, d2 = d.z * 0.2f, d3 = d.w * 0.2f;
  float ah = r.z - r.x, aw = r.w - r.y;
  float acy = r.x + 0.5f * ah, acx = r.y + 0.5f * aw;
  float bh = expf(d2) * ah, bw = expf(d3) * aw;
  float bcy = d0 * ah + acy, bcx = d1 * aw + acx;
  float y1 = bcy - 0.5f * bh, x1 = bcx - 0.5f * bw;
  float y2 = y1 + bh, x2 = x1 + bw;
  y1 = fminf(fmaxf(y1, 0.f), 1.f); x1 = fminf(fmaxf(x1, 0.f), 1.f);
  y2 = fminf(fmaxf(y2, 0.f), 1.f); x2 = fminf(fmaxf(x2, 0.f), 1.f);
  return make_float4(y1, x1, y2, x2);
}

// IoU with the reference's exact association: ((sel_a + area) - inter) + 1e-8.
__device__ __forceinline__ float iou_ref(float4 s, float4 o) {
#pragma clang fp contract(off)
  float iy1 = fmaxf(s.x, o.x), ix1 = fmaxf(s.y, o.y);
  float iy2 = fminf(s.z, o.z), ix2 = fminf(s.w, o.w);
  float inter = fmaxf(iy2 - iy1, 0.f) * fmaxf(ix2 - ix1, 0.f);
  float sa = fmaxf(s.z - s.x, 0.f) * fmaxf(s.w - s.y, 0.f);
  float oa = fmaxf(o.z - o.x, 0.f) * fmaxf(o.w - o.y, 0.f);
  return inter / (sa + oa - inter + 1e-08f);
}

// Per-anchor argmax (identical expression to rounds 1-7 label_kernel: strict >,
// first max wins) + masked-score TRANSPOSE: probsT[b][c][n] = am ? pr[c] : 0.
// Writes are lane-consecutive in n -> coalesced. Round-8 lesson: fusing the
// argmax into nms made all 21 class-blocks re-read 21 probs/anchor (FETCH
// 20.4->23.4 MB, nms 54->59.5 us); nms's strided probs column reads (4B at
// 84B stride = 64 lines/wave) were the real phase-1 cost all along.
__global__ __launch_bounds__(256) void prep_kernel(
    const float* __restrict__ probs, float* __restrict__ probsT)
{
  int t = blockIdx.x * 256 + threadIdx.x;
  if (t >= B_ * N_) return;
  int b = t / N_, n = t - b * N_;
  const float* pr = probs + (size_t)t * C_;
  float p[C_];
  #pragma unroll
  for (int k = 0; k < C_; ++k) p[k] = pr[k];
  float mx = p[0]; int am = 0;
  #pragma unroll
  for (int k = 1; k < C_; ++k) { if (p[k] > mx) { mx = p[k]; am = k; } }
  float msk = (am != 0) ? 1.0f : 0.0f;
  #pragma unroll
  for (int c = 0; c < C_; ++c)
    probsT[((size_t)b * C_ + c) * N_ + n] = p[c] * msk;   // exact: *1.0f == copy
}

// One block per (b,c). Phase 2 is round-8 verbatim (banked: passed + replay
// tripwires). Phase 1: if probsT != nullptr, read this block's coalesced
// masked-score row (candidate set & key bits identical to the probs/amask
// path); else fall back to round-8's inline-argmax scan (small-ws tier).
__global__ __launch_bounds__(NTH) void nms_kernel(
    const float* __restrict__ roi, const float* __restrict__ deltas,
    const float* __restrict__ probs, const float* __restrict__ probsT,
    float* __restrict__ sel_val, float* __restrict__ sel_box)
{
#pragma clang fp contract(off)
  const int bc = blockIdx.x, b = bc / C_, c = bc % C_;
  const int tid = threadIdx.x, lane = tid & 63, wv = tid >> 6;

  __shared__ unsigned long long ukeys[UCAP];     // unordered candidate keys
  __shared__ unsigned long long cbuf[CCAP];      // current chunk (sorted)
  __shared__ float4 cboxAll[CCAP];               // decoded chunk boxes
  __shared__ float4 comm[MAXT];                  // committed (selected) boxes
  __shared__ unsigned long long kill[64];        // intra-batch kill rows
  __shared__ unsigned long long s_dead[16];      // per-wave vs-committed masks
  __shared__ int hist[NBUCK];
  __shared__ int s_cnt, s_clen, s_ncomm, s_blo, s_len;

  if (tid < NBUCK) hist[tid] = 0;
  if (tid == 0) { s_cnt = 0; s_ncomm = 0; }
  __syncthreads();

  // ---- Phase 1: threshold + collect keys + histogram ----
  // (scores in (0.5,1) => exponent fixed at 126 => mantissa bits are a
  //  monotone prefix of ford(score); bucket = mantissa bits 22..17)
  const float* rowT = probsT ? (probsT + (size_t)bc * N_) : nullptr;
  for (int base0 = 0; base0 < N_; base0 += NTH) {
    int n = base0 + tid;
    bool cand = false;
    float sc = 0.f;
    if (rowT) {
      sc = (n < N_) ? rowT[n] : 0.f;     // coalesced 4B wave-load
      cand = (sc > 0.5f);
    } else if (n < N_) {
      const float* pr = probs + ((size_t)b * N_ + n) * C_;
      float mx = pr[0]; int am = 0;
      #pragma unroll
      for (int k = 1; k < C_; ++k) { float v = pr[k]; if (v > mx) { mx = v; am = k; } }
      if (am != 0) sc = pr[c];
      cand = (sc > 0.5f);
    }
    unsigned long long m = __ballot(cand);
    int wcnt = __popcll(m);
    int bslot = 0;
    if (lane == 0 && wcnt) bslot = atomicAdd(&s_cnt, wcnt);
    bslot = __shfl(bslot, 0);
    if (cand) {
      int pos = bslot + __popcll(m & ((1ULL << lane) - 1ULL));
      if (pos < UCAP) {
        unsigned hi = ford(sc);
        ukeys[pos] = ((unsigned long long)hi << 32) |
                     (unsigned)(0xFFFFFFFFu - (unsigned)n);
        atomicAdd(&hist[(hi >> 17) & (NBUCK - 1)], 1);
      }
    }
  }
  __syncthreads();
  int M = s_cnt < UCAP ? s_cnt : UCAP;

  float* sv = sel_val + (size_t)bc * MAXT;
  float* sb = sel_box + (size_t)bc * MAXT * 4;

  // ---- Phase 2: chunked sort + walk (round-8 verbatim) ----
  int bhi = NBUCK - 1;
  while (true) {
    if (s_ncomm >= MAXT || bhi < 0) break;

    if (tid == 0) {
      int tot = 0, lo = bhi;
      while (lo >= 0) {
        int t2 = tot + hist[lo];
        if (t2 > CTGT && tot > 0) break;
        tot = t2; --lo;
        if (tot > CTGT) break;
      }
      s_blo = lo + 1; s_len = tot; s_clen = 0;
    }
    __syncthreads();
    int blo = s_blo;
    if (s_len == 0) break;            // all remaining buckets empty

    // gather chunk members from unordered keys (order random; sort fixes it)
    for (int i = tid; i < M; i += NTH) {
      unsigned long long kk = ukeys[i];
      int bk = (int)((kk >> 49) & (NBUCK - 1));
      bool in = (bk >= blo && bk <= bhi);
      unsigned long long mm = __ballot(in);
      int wc = __popcll(mm);
      int bs0 = 0;
      if (lane == 0 && wc) bs0 = atomicAdd(&s_clen, wc);
      bs0 = __shfl(bs0, 0);
      if (in) {
        int p = bs0 + __popcll(mm & ((1ULL << lane) - 1ULL));
        if (p < CCAP) cbuf[p] = kk;
      }
    }
    __syncthreads();
    int alen = s_clen < CCAP ? s_clen : CCAP;

    if (alen > 0) {
      int SORTP = 64;
      while (SORTP < alen) SORTP <<= 1;

      // bitonic sort desc, 1 elem/lane: j<64 via shfl_xor, j>=64 via LDS.
      {
        unsigned long long v = (tid < alen) ? cbuf[tid] : 0ULL;
        for (int k = 2; k <= SORTP; k <<= 1) {
          for (int j = k >> 1; j > 0; j >>= 1) {
            bool takeMax = ((tid & j) == 0) == ((tid & k) == 0);
            unsigned long long w;
            if (j >= 64) {
              __syncthreads(); cbuf[tid] = v; __syncthreads();
              w = cbuf[tid ^ j];
            } else {
              w = __shfl_xor(v, j);
            }
            if ((w > v) == takeMax) v = w;
          }
        }
        __syncthreads(); cbuf[tid] = v; __syncthreads();
      }

      // upfront decode of the whole sorted chunk
      if (tid < alen) {
        int n = (int)(0xFFFFFFFFu - (unsigned)(cbuf[tid] & 0xFFFFFFFFull));
        cboxAll[tid] = decode_box(roi, deltas, b, n, c);
      }
      __syncthreads();

      // walk the sorted chunk in batches of 64 (2 barriers per batch)
      int start = 0;
      while (true) {
        int nc = s_ncomm;
        if (nc >= MAXT || start >= alen) break;
        int bs = min(64, alen - start);

        float4 ib = cboxAll[start + lane];
        #pragma unroll
        for (int r = 0; r < 4; ++r) {
          int j = (wv << 2) | r;
          float4 jb4 = cboxAll[start + j];
          bool kf = (j < bs) && (lane < bs) && (lane > j) &&
                    (iou_ref(jb4, ib) > 0.5f);
          unsigned long long rowm = __ballot(kf);
          if (lane == 0) kill[j] = rowm;
        }
        {
          bool dead = false;
          if (lane < bs) {
            for (int jc = wv; jc < nc; jc += 16) {
              if (iou_ref(comm[jc], ib) > 0.5f) { dead = true; break; }
            }
          }
          unsigned long long dm = __ballot(dead);
          if (lane == 0) s_dead[wv] = dm;
        }
        __syncthreads();

        if (wv == 0) {
          unsigned long long sup = s_dead[0];
          for (int w2 = 1; w2 < 16; ++w2) sup |= s_dead[w2];
          unsigned long long myrow = kill[lane];
          unsigned long long alive = ~sup;
          if (bs < 64) alive &= ((1ULL << bs) - 1ULL);
          unsigned long long chosen = 0ULL;
          int cnt = nc;
          for (int j = 0; j < bs && cnt < MAXT; ++j) {
            if (!((alive >> j) & 1ULL)) continue;
            chosen |= (1ULL << j);
            ++cnt;
            alive &= ~__shfl(myrow, j);
          }
          if ((chosen >> lane) & 1ULL) {
            int rnk = nc + __popcll(chosen & ((1ULL << lane) - 1ULL));
            float4 bb2 = cboxAll[start + lane];
            comm[rnk] = bb2;
            sv[rnk] = funord((unsigned)(cbuf[start + lane] >> 32));
            sb[(size_t)rnk * 4 + 0] = bb2.x; sb[(size_t)rnk * 4 + 1] = bb2.y;
            sb[(size_t)rnk * 4 + 2] = bb2.z; sb[(size_t)rnk * 4 + 3] = bb2.w;
          }
          if (lane == 0) s_ncomm = cnt;
        }
        __syncthreads();
        start += bs;
      }
    }
    bhi = blo - 1;
  }

  // remaining steps invalid -> sel_val = NEG (boxes never read for these)
  int T = s_ncomm;
  for (int j2 = T + tid; j2 < MAXT; j2 += NTH) sv[j2] = NEGV;
}

// ---- Merge, stage 1: per-(b, searched-class) partial ranks.
// Writes CLASS-MAJOR partial[blk][e] — consecutive e per lane -> coalesced
// (round 7/8 wrote entry-major: 84-B-stride scatter, 64 lines/wave).
__global__ __launch_bounds__(NTH) void rank_kernel(
    const float* __restrict__ sel_val, int* __restrict__ partial)
{
  const int blk = blockIdx.x;          // b * C_ + sc
  const int b = blk / C_, sc = blk % C_;
  const int tid = threadIdx.x;
  __shared__ unsigned long long lkeys[MAXT];

  if (tid < MAXT) {
    float v = sel_val[(size_t)b * NENT + sc * MAXT + tid];
    lkeys[tid] = ((unsigned long long)ford(v) << 32) |
                 (unsigned)(0xFFFFFFFFu - (unsigned)(sc * MAXT + tid));
  }
  __syncthreads();

  for (int e = tid; e < NENT; e += NTH) {
    float v = sel_val[(size_t)b * NENT + e];
    unsigned long long mykey = ((unsigned long long)ford(v) << 32) |
                               (unsigned)(0xFFFFFFFFu - (unsigned)e);
    int lo = 0, hi = MAXT;
    while (lo < hi) {
      int mid = (lo + hi) >> 1;
      if (lkeys[mid] > mykey) lo = mid + 1; else hi = mid;
    }
    partial[(size_t)blk * NENT + e] = lo;   // coalesced
  }
}

// ---- Merge, stage 2: rank = sum of 21 per-class planes -> scatter.
// For fixed cc, lanes read consecutive e -> coalesced. Ranks are a
// permutation of 0..NENT-1; ranks < 200 cover every output slot once.
__global__ __launch_bounds__(256) void scatter_kernel(
    const float* __restrict__ sel_val, const float* __restrict__ sel_box,
    const int* __restrict__ partial, float* __restrict__ out)
{
  const int blk = blockIdx.x;          // b * C_ + sc
  const int b = blk / C_, sc = blk % C_;
  const int t = threadIdx.x;
  if (t >= MAXT) return;
  const int e = sc * MAXT + t;

  int rank = 0;
  #pragma unroll
  for (int cc = 0; cc < C_; ++cc)
    rank += partial[((size_t)b * C_ + cc) * NENT + e];   // coalesced per cc
  if (rank >= MAXT) return;

  float* obx = out + (size_t)b * MAXT * 4;                       // final_bboxes
  float* olb = out + (size_t)B_ * MAXT * 4 + (size_t)b * MAXT;   // final_labels
  float* osc = out + (size_t)B_ * MAXT * 5 + (size_t)b * MAXT;   // final_scores

  float v = sel_val[(size_t)b * NENT + e];
  if (v > NEGV * 0.5f) {
    osc[rank] = v;
    olb[rank] = (float)sc;
    const float* bp = sel_box + ((size_t)b * NENT + e) * 4;
    obx[rank * 4 + 0] = bp[0]; obx[rank * 4 + 1] = bp[1];
    obx[rank * 4 + 2] = bp[2]; obx[rank * 4 + 3] = bp[3];
  } else {
    osc[rank] = 0.f; olb[rank] = 0.f;
    obx[rank * 4 + 0] = 0.f; obx[rank * 4 + 1] = 0.f;
    obx[rank * 4 + 2] = 0.f; obx[rank * 4 + 3] = 0.f;
  }
}

// Fallback merge (used only if ws can't hold partials).
__global__ __launch_bounds__(NTH) void merge_kernel(
    const float* __restrict__ sel_val, const float* __restrict__ sel_box,
    float* __restrict__ out)
{
  const int b = blockIdx.x;
  const int tid = threadIdx.x;
  __shared__ float svl[NENT];
  for (int i = tid; i < NENT; i += NTH)
    svl[i] = sel_val[(size_t)b * NENT + i];
  __syncthreads();

  float* obx = out + (size_t)b * MAXT * 4;
  float* olb = out + (size_t)B_ * MAXT * 4 + (size_t)b * MAXT;
  float* osc = out + (size_t)B_ * MAXT * 5 + (size_t)b * MAXT;

  for (int e = tid; e < NENT; e += NTH) {
    float v = svl[e];
    unsigned long long mykey = ((unsigned long long)ford(v) << 32) |
                               (unsigned)(0xFFFFFFFFu - (unsigned)e);
    int rank = 0;
    for (int cc = 0; cc < C_; ++cc) {
      int lo = 0, hi = MAXT;
      while (lo < hi) {
        int mid = (lo + hi) >> 1;
        int ee = cc * MAXT + mid;
        unsigned long long k2 = ((unsigned long long)ford(svl[ee]) << 32) |
                                (unsigned)(0xFFFFFFFFu - (unsigned)ee);
        if (k2 > mykey) lo = mid + 1; else hi = mid;
      }
      rank += lo;
    }
    if (rank < MAXT) {
      if (v > NEGV * 0.5f) {
        osc[rank] = v;
        olb[rank] = (float)(e / MAXT);
        const float* bp = sel_box + ((size_t)b * NENT + e) * 4;
        obx[rank * 4 + 0] = bp[0]; obx[rank * 4 + 1] = bp[1];
        obx[rank * 4 + 2] = bp[2]; obx[rank * 4 + 3] = bp[3];
      } else {
        osc[rank] = 0.f; olb[rank] = 0.f;
        obx[rank * 4 + 0] = 0.f; obx[rank * 4 + 1] = 0.f;
        obx[rank * 4 + 2] = 0.f; obx[rank * 4 + 3] = 0.f;
      }
    }
  }
}

extern "C" void kernel_launch(void* const* d_in, const int* in_sizes, int n_in,
                              void* d_out, int out_size, void* d_ws, size_t ws_size,
                              hipStream_t stream)
{
  const float* roi    = (const float*)d_in[0];  // (8,6000,4)
  const float* deltas = (const float*)d_in[1];  // (8,6000,84)
  const float* probs  = (const float*)d_in[2];  // (8,6000,21)
  float* out = (float*)d_out;                   // 6400 + 1600 + 1600 floats
  float* ws  = (float*)d_ws;

  // ws layout (floats): sel_val[33600] | sel_box[134400] | probsT[1008000] |
  //                     partial[705600 ints]
  float* sel_val = ws;
  float* sel_box = ws + (size_t)B_ * NENT;
  float* probsT  = ws + (size_t)B_ * NENT * 5;
  int*   partial = (int*)(ws + (size_t)B_ * NENT * 5 + (size_t)B_ * C_ * N_);

  size_t base_f   = (size_t)B_ * NENT * 5;
  size_t need_mid  = (base_f + (size_t)B_ * C_ * N_) * sizeof(float);
  size_t need_full = need_mid + (size_t)B_ * C_ * NENT * sizeof(int);

  const float* probsT_arg = (ws_size >= need_mid) ? probsT : nullptr;
  if (probsT_arg)
    prep_kernel<<<dim3((B_ * N_ + 255) / 256), dim3(256), 0, stream>>>(probs, probsT);

  nms_kernel<<<dim3(B_ * C_), dim3(NTH), 0, stream>>>(
      roi, deltas, probs, probsT_arg, sel_val, sel_box);

  if (ws_size >= need_full) {
    rank_kernel<<<dim3(B_ * C_), dim3(NTH), 0, stream>>>(sel_val, partial);
    scatter_kernel<<<dim3(B_ * C_), dim3(256), 0, stream>>>(sel_val, sel_box, partial, out);
  } else {
    merge_kernel<<<dim3(B_), dim3(NTH), 0, stream>>>(sel_val, sel_box, out);
  }
}